// Round 12
// baseline (365.627 us; speedup 1.0000x reference)
//
#include <hip/hip_runtime.h>
#include <math.h>

#define NPAPER 100000
#define NAUTH  50000
#define DIM    128
#define NEDGE  500000
#define NCLS   16
#define NTOT   (2*NPAPER + NAUTH)   // concatenated CSR node space (C | W | R)
#define NB     245                  // buckets of 1024 nodes over NTOT
#define CHUNK_A 11776               // edges per bucketize block
#define NBLK_A  128                 // ceil(3*NEDGE / CHUNK_A)
#define PBLK   ((NPAPER + 127) / 128)   // 782
#define ABLK   ((NAUTH  + 127) / 128)   // 391

typedef unsigned int   uint;
typedef unsigned short ushort;
typedef unsigned char  uchar;
using short8 = __attribute__((ext_vector_type(8))) short;
using f32x4  = __attribute__((ext_vector_type(4))) float;

__device__ __forceinline__ float b2f(uint u) {
    return __uint_as_float(u << 16);
}
__device__ __forceinline__ ushort f2b(float f) {   // round-to-nearest-even
    uint x = __float_as_uint(f);
    return (ushort)((x + 0x7fffu + ((x >> 16) & 1u)) >> 16);
}

// global_load_lds: linear LDS dest (wave base + lane*16), per-lane global src.
#define GLD_LDS16(srcp, ldsp) \
    __builtin_amdgcn_global_load_lds( \
        (const __attribute__((address_space(1))) void*)(srcp), \
        (__attribute__((address_space(3))) void*)(ldsp), 16, 0, 0)

// ---------------------------------------------------------------------------
// prep bodies (block-indexed device functions, merged into lean misc kernels)
// ---------------------------------------------------------------------------
__device__ __forceinline__ void prep_weights_body(int b, int tid,
    const float* __restrict__ Wl, const float* __restrict__ Wr,
    const float* __restrict__ bl,
    float* __restrict__ Bp, float* __restrict__ Ba,
    float* __restrict__ biasp, float* __restrict__ biasa)
{
    int t = b * 256 + tid;
    if (t < 2*384*128) {
        int l = t / (384*128); int rem = t - l*(384*128);
        int k = rem >> 7, j = rem & 127;
        float v;
        if (k < 128)      v = Wl[((l*3+0)*128 + j)*128 + k];
        else if (k < 256) v = Wl[((l*3+1)*128 + j)*128 + (k-128)];
        else              v = Wr[((l*3+0)*128 + j)*128 + (k-256)]
                            + Wr[((l*3+1)*128 + j)*128 + (k-256)];
        Bp[t] = v;
        return;
    }
    t -= 2*384*128;
    if (t < 2*256*128) {
        int l = t / (256*128); int rem = t - l*(256*128);
        int k = rem >> 7, j = rem & 127;
        Ba[t] = (k < 128) ? Wl[((l*3+2)*128 + j)*128 + k]
                          : Wr[((l*3+2)*128 + j)*128 + (k-128)];
        return;
    }
    t -= 2*256*128;
    if (t < 256) { int l=t>>7, j=t&127; biasp[t] = bl[(l*3+0)*128+j] + bl[(l*3+1)*128+j]; return; }
    t -= 256;
    if (t < 256) { int l=t>>7, j=t&127; biasa[t] = bl[(l*3+2)*128+j]; return; }
}

// residual fold + bf16 + PACK into MFMA-fragment order.
__device__ __forceinline__ size_t pack_off(int j, int k) {
    int kstep = k >> 6, ks = (k >> 5) & 1, g4 = (k >> 3) & 3, jj = k & 7;
    int f = j >> 4, l15 = j & 15;
    return (size_t)kstep*8192 + (size_t)(ks*512 + f*64 + g4*16 + l15)*8 + jj;
}

__device__ __forceinline__ void build_bt_body(int b, int tid,
    const float* __restrict__ Bp, const float* __restrict__ Ba,
    const float* __restrict__ linp, const float* __restrict__ lina,
    ushort* __restrict__ Btp, ushort* __restrict__ Bta)
{
    int t = b * 256 + tid;
    if (t < 2*128*384) {
        int l = t / (128*384); int rem = t - l*(128*384);
        int j = rem / 384, k = rem - j*384;
        const float* brow = Bp + (size_t)l*384*128 + (size_t)k*128;
        float v = brow[j];
        if (l == 0) {
            const float* lrow = linp + (size_t)j*128;
            float s = 0.f;
            #pragma unroll 8
            for (int m = 0; m < 128; m++) s += brow[m] * lrow[m];
            v += s;
        }
        Btp[(size_t)l*49152 + pack_off(j, k)] = f2b(v);
        return;
    }
    t -= 2*128*384;
    if (t < 2*128*256) {
        int l = t / (128*256); int rem = t - l*(128*256);
        int j = rem / 256, k = rem - j*256;
        const float* brow = Ba + (size_t)l*256*128 + (size_t)k*128;
        float v = brow[j];
        if (l == 0) {
            const float* lrow = lina + (size_t)j*128;
            float s = 0.f;
            #pragma unroll 8
            for (int m = 0; m < 128; m++) s += brow[m] * lrow[m];
            v += s;
        }
        Bta[(size_t)l*32768 + pack_off(j, k)] = f2b(v);
    }
}

__device__ __forceinline__ void fold_bias_body(int b, int tid,
    const float* __restrict__ biasp, const float* __restrict__ biasa,
    const float* __restrict__ linp, const float* __restrict__ lina,
    float* __restrict__ biasp2, float* __restrict__ biasa2)
{
    int t = b * 256 + tid;   // 512 total
    int isa = t >> 8; int r = t & 255;
    int l = r >> 7, j = r & 127;
    const float* bsrc = isa ? biasa : biasp;
    const float* lin  = isa ? lina  : linp;
    float v = bsrc[r];
    if (l == 0) {
        float s = 0.f;
        for (int k = 0; k < 128; k++) s += bsrc[k] * lin[j*128 + k];
        v += s;
    }
    (isa ? biasa2 : biasp2)[r] = v;
}

__device__ __forceinline__ void to_bf16_body(int b, int tid,
    const float* __restrict__ xp, const float* __restrict__ xa,
    ushort* __restrict__ yp, ushort* __restrict__ ya)
{
    int i = b * 256 + tid;
    const int n4p = NPAPER * DIM / 4;
    const float* x; ushort* y;
    if (i < n4p) { x = xp; y = yp; }
    else { x = xa; y = ya; i -= n4p; }
    float4 v = ((const float4*)x)[i];
    uint2 o;
    o.x = (uint)f2b(v.x) | ((uint)f2b(v.y) << 16);
    o.y = (uint)f2b(v.z) | ((uint)f2b(v.w) << 16);
    ((uint2*)y)[i] = o;
}

// ---------------------------------------------------------------------------
__device__ __forceinline__ int edge_g(const int* __restrict__ eiC,
                                      const int* __restrict__ eiW,
                                      const int* __restrict__ eiR, int i)
{
    int tpe = (i >= 2*NEDGE) ? 2 : ((i >= NEDGE) ? 1 : 0);
    int e = i - tpe*NEDGE;
    const int* ei = (tpe == 0) ? eiC : ((tpe == 1) ? eiW : eiR);
    int base = (tpe == 0) ? 0 : ((tpe == 1) ? NPAPER : 2*NPAPER);
    return base + ei[NEDGE + e];
}

// misc0: [bucket_count (128) | prep_weights (642) | to_bf16 (18750)]
#define PREPB 642
__global__ __launch_bounds__(256) void misc0(
    const int* __restrict__ eiC, const int* __restrict__ eiW,
    const int* __restrict__ eiR, int* __restrict__ bucketCount,
    const float* __restrict__ Wl, const float* __restrict__ Wr,
    const float* __restrict__ bl,
    float* __restrict__ Bp, float* __restrict__ Ba,
    float* __restrict__ biasp, float* __restrict__ biasa,
    const float* __restrict__ xpf, const float* __restrict__ xaf,
    ushort* __restrict__ xpb, ushort* __restrict__ xab)
{
    __shared__ int h[256];
    int b = blockIdx.x, t = threadIdx.x;
    if (b < NBLK_A) {
        h[t] = 0;
        __syncthreads();
        int start = b * CHUNK_A;
        int n = 3*NEDGE - start; if (n > CHUNK_A) n = CHUNK_A;
        for (int i = t; i < n; i += 256)
            atomicAdd(&h[edge_g(eiC, eiW, eiR, start + i) >> 10], 1);
        __syncthreads();
        if (h[t]) atomicAdd(&bucketCount[t], h[t]);
        return;
    }
    b -= NBLK_A;
    if (b < PREPB) {
        prep_weights_body(b, t, Wl, Wr, bl, Bp, Ba, biasp, biasa);
        return;
    }
    b -= PREPB;
    to_bf16_body(b, t, xpf, xaf, xpb, xab);
}

// misc1: [fold_bias (2) | build_bt (640) | bucket_emit (128)]
// Emit blocks compute the 245-bin exclusive scan redundantly from bucketCount
// (tiny) and reserve per-bucket ranges via zero-initialized emitCursor.
#define BTB 640
__global__ __launch_bounds__(256) void misc1(
    const float* __restrict__ biasp, const float* __restrict__ biasa,
    const float* __restrict__ linp, const float* __restrict__ lina,
    float* __restrict__ biasp2, float* __restrict__ biasa2,
    const float* __restrict__ Bp, const float* __restrict__ Ba,
    ushort* __restrict__ Btp, ushort* __restrict__ Bta,
    const int* __restrict__ eiC, const int* __restrict__ eiW,
    const int* __restrict__ eiR,
    const int* __restrict__ bucketCount, int* __restrict__ emitCursor,
    uint2* __restrict__ stage)
{
    int blk = blockIdx.x, t = threadIdx.x;
    if (blk < 2) {
        fold_bias_body(blk, t, biasp, biasa, linp, lina, biasp2, biasa2);
        return;
    }
    blk -= 2;
    if (blk < BTB) {
        build_bt_body(blk, t, Bp, Ba, linp, lina, Btp, Bta);
        return;
    }
    int b = blk - BTB;

    __shared__ uchar  bId [CHUNK_A];
    __shared__ ushort rnk [CHUNK_A];
    __shared__ ushort perm[CHUNK_A];
    __shared__ uchar  posB[CHUNK_A];
    __shared__ int lcnt[256];
    __shared__ int lpre[256];
    __shared__ int bbase[256];
    __shared__ int bbs[256];

    // redundant exclusive scan of bucketCount -> bucket bases
    {
        int v = (t < NB) ? bucketCount[t] : 0;
        bbs[t] = v;
        __syncthreads();
        for (int o = 1; o < 256; o <<= 1) {
            int x = (t >= o) ? bbs[t - o] : 0;
            __syncthreads();
            bbs[t] += x;
            __syncthreads();
        }
        int inc = bbs[t];
        __syncthreads();
        bbs[t] = inc - ((t < NB) ? bucketCount[t] : 0);   // exclusive
        __syncthreads();
    }

    int start = b * CHUNK_A;
    int n = 3*NEDGE - start; if (n > CHUNK_A) n = CHUNK_A;
    lcnt[t] = 0;
    __syncthreads();
    for (int i = t; i < n; i += 256) {
        int bb = edge_g(eiC, eiW, eiR, start + i) >> 10;
        bId[i] = (uchar)bb;
        rnk[i] = (ushort)atomicAdd(&lcnt[bb], 1);
    }
    __syncthreads();
    lpre[t] = lcnt[t];
    __syncthreads();
    for (int o = 1; o < 256; o <<= 1) {
        int x = (t >= o) ? lpre[t - o] : 0;
        __syncthreads();
        lpre[t] += x;
        __syncthreads();
    }
    if (lcnt[t] > 0) bbase[t] = bbs[t] + atomicAdd(&emitCursor[t], lcnt[t]);
    __syncthreads();
    for (int i = t; i < n; i += 256) {
        int bb = bId[i];
        int p = (lpre[bb] - lcnt[bb]) + rnk[i];
        perm[p] = (ushort)i;
        posB[p] = (uchar)bb;
    }
    __syncthreads();
    for (int p = t; p < n; p += 256) {
        int bb = posB[p];
        int i = start + perm[p];
        int tpe = (i >= 2*NEDGE) ? 2 : ((i >= NEDGE) ? 1 : 0);
        int e = i - tpe*NEDGE;
        const int* ei = (tpe == 0) ? eiC : ((tpe == 1) ? eiW : eiR);
        int base = (tpe == 0) ? 0 : ((tpe == 1) ? NPAPER : 2*NPAPER);
        uint2 o2;
        o2.x = (uint)(base + ei[NEDGE + e]);
        o2.y = (uint)ei[e];
        stage[bbase[bb] + (p - (lpre[bb] - lcnt[bb]))] = o2;
    }
}

// Per-bucket CSR finalize; bucket bases scanned inline from bucketCount.
__global__ __launch_bounds__(256) void csr_fillB(
    const uint2* __restrict__ stage, const int* __restrict__ bucketCount,
    int* __restrict__ rowAll, int* __restrict__ colAll)
{
    __shared__ int cnt[1024];
    __shared__ int part[256];
    __shared__ int bbs[256];
    int b = blockIdx.x;
    int t = threadIdx.x;

    // inline exclusive scan of bucketCount
    {
        int v = (t < NB) ? bucketCount[t] : 0;
        bbs[t] = v;
        __syncthreads();
        for (int o = 1; o < 256; o <<= 1) {
            int x = (t >= o) ? bbs[t - o] : 0;
            __syncthreads();
            bbs[t] += x;
            __syncthreads();
        }
        int inc = bbs[t];
        __syncthreads();
        bbs[t] = inc - ((t < NB) ? bucketCount[t] : 0);
        __syncthreads();
    }
    int g0 = b << 10;
    int nn = NTOT - g0; if (nn > 1024) nn = 1024;
    int s = bbs[b];
    int e = s + bucketCount[b];

    #pragma unroll
    for (int i = t; i < 1024; i += 256) cnt[i] = 0;
    __syncthreads();
    for (int i = s + t; i < e; i += 256) atomicAdd(&cnt[(int)stage[i].x - g0], 1);
    __syncthreads();
    int loc[4]; int ss = 0;
    #pragma unroll
    for (int j = 0; j < 4; j++) { loc[j] = cnt[t*4 + j]; ss += loc[j]; }
    part[t] = ss;
    __syncthreads();
    for (int o = 1; o < 256; o <<= 1) {
        int x = (t >= o) ? part[t - o] : 0;
        __syncthreads();
        part[t] += x;
        __syncthreads();
    }
    int run = (t > 0) ? part[t-1] : 0;
    #pragma unroll
    for (int j = 0; j < 4; j++) { int c = loc[j]; cnt[t*4 + j] = run; run += c; }
    __syncthreads();
    for (int i = t; i < nn; i += 256) rowAll[g0 + i] = s + cnt[i];
    if (b == NB-1 && t == 0) rowAll[NTOT] = 3*NEDGE;
    __syncthreads();
    for (int i = s + t; i < e; i += 256) {
        uint2 ed = stage[i];
        int slot = atomicAdd(&cnt[(int)ed.x - g0], 1);
        colAll[s + slot] = (int)ed.y;
    }
}

// ---------------------------------------------------------------------------
// Gather-mean: ONE NODE PER WAVE (64 lanes x 4B = 256B/row, one instr/edge).
// No intra-wave divergence (all lanes share the node's degree loop).
__global__ __launch_bounds__(256) void gather_seg(
    int g0, int g1,
    const ushort* __restrict__ xp, const ushort* __restrict__ xa,
    const int* __restrict__ rowAll, const int* __restrict__ colAll,
    ushort* __restrict__ aggC, ushort* __restrict__ aggW,
    ushort* __restrict__ aggR)
{
    int g = g0 + ((blockIdx.x * 256 + threadIdx.x) >> 6);
    int lane = threadIdx.x & 63;
    if (g >= g1) return;
    const ushort* xs; ushort* out; int node;
    if (g < NPAPER)        { node = g;            xs = xp; out = aggC; }
    else if (g < 2*NPAPER) { node = g - NPAPER;   xs = xa; out = aggW; }
    else                   { node = g - 2*NPAPER; xs = xp; out = aggR; }

    int s = rowAll[g], e = rowAll[g + 1];
    float a0 = 0.f, a1 = 0.f, b0 = 0.f, b1 = 0.f;
    int j = s;
    #pragma unroll 1
    for (; j + 4 <= e; j += 4) {
        int s0 = colAll[j], s1 = colAll[j+1], s2 = colAll[j+2], s3 = colAll[j+3];
        uint v0 = *(const uint*)(xs + (size_t)s0 * DIM + lane * 2);
        uint v1 = *(const uint*)(xs + (size_t)s1 * DIM + lane * 2);
        uint v2 = *(const uint*)(xs + (size_t)s2 * DIM + lane * 2);
        uint v3 = *(const uint*)(xs + (size_t)s3 * DIM + lane * 2);
        a0 += b2f(v0 & 0xffffu); a1 += b2f(v0 >> 16);
        b0 += b2f(v1 & 0xffffu); b1 += b2f(v1 >> 16);
        a0 += b2f(v2 & 0xffffu); a1 += b2f(v2 >> 16);
        b0 += b2f(v3 & 0xffffu); b1 += b2f(v3 >> 16);
    }
    #pragma unroll 1
    for (; j < e; j++) {
        uint v = *(const uint*)(xs + (size_t)colAll[j] * DIM + lane * 2);
        a0 += b2f(v & 0xffffu); a1 += b2f(v >> 16);
    }
    float inv = (e > s) ? 1.f / (float)(e - s) : 0.f;
    a0 = (a0 + b0) * inv;
    a1 = (a1 + b1) * inv;
    uint o = (uint)f2b(a0) | ((uint)f2b(a1) << 16);
    *(uint*)(out + (size_t)node * DIM + lane * 2) = o;
}

// ---------------------------------------------------------------------------
// Merged MFMA GEMM + bias + LayerNorm + ReLU.  Blocks [0,pblk): paper rows
// (K=384, segs aggC|aggW|self-p); blocks [pblk,..): author rows (K=256,
// segs aggR|self-a).  256 thr / 4 waves / 128 rows / full N=128 / K-step 64.
__global__ __launch_bounds__(256) void gemm_ln2(
    const ushort* __restrict__ aggC, const ushort* __restrict__ aggW,
    const ushort* __restrict__ aggR,
    const ushort* __restrict__ xp, const ushort* __restrict__ xa,
    const ushort* __restrict__ Btp, const ushort* __restrict__ Bta,
    const float* __restrict__ biasp, const float* __restrict__ biasa,
    const float* __restrict__ lns, const float* __restrict__ lnb,
    ushort* __restrict__ outp, ushort* __restrict__ outa, int pblk)
{
    __shared__ ushort As[8192];   // 16 KB, one K-step
    __shared__ ushort Bs[8192];   // 16 KB

    bool isp = (int)blockIdx.x < pblk;
    int  bid = isp ? blockIdx.x : (blockIdx.x - pblk);
    int  N   = isp ? NPAPER : NAUTH;
    int  K   = isp ? 384 : 256;
    const ushort* A0 = isp ? aggC : aggR;
    const ushort* A1 = isp ? aggW : xa;
    const ushort* A2 = isp ? xp   : xa;
    const ushort* Bt = isp ? Btp  : Bta;
    const float* bias = isp ? biasp : biasa;
    const float* lng  = lns + (isp ? 0 : 128);
    const float* lnbb = lnb + (isp ? 0 : 128);
    ushort* out = isp ? outp : outa;

    int t    = threadIdx.x;
    int w    = t >> 6;
    int lane = t & 63;
    int row0 = bid * 128;
    int l15  = lane & 15;
    int g4   = lane >> 4;

    f32x4 acc0[8], acc1[8];
    #pragma unroll
    for (int f = 0; f < 8; f++) {
        acc0[f] = (f32x4){0.f, 0.f, 0.f, 0.f};
        acc1[f] = (f32x4){0.f, 0.f, 0.f, 0.f};
    }

    int nstep = K >> 6;
    for (int st = 0; st < nstep; st++) {
        int kk  = st << 6;
        int seg = kk >> 7, kl = kk & 127;
        const ushort* Ap = (seg == 0) ? A0 : ((seg == 1) ? A1 : A2);

        #pragma unroll
        for (int p = 0; p < 4; p++) {
            int q  = p*256 + t;
            int ks = q >> 9, rb = (q >> 6) & 7, l = q & 63;
            int row = row0 + rb*16 + (l & 15);
            row = (row < N) ? row : (N - 1);
            int k = kl + ks*32 + (l >> 4)*8;
            int qbase = p*256 + w*64;
            GLD_LDS16(Ap + (size_t)row*DIM + k, As + qbase*8);
        }
        #pragma unroll
        for (int p = 0; p < 4; p++) {
            int q = p*256 + t;
            int qbase = p*256 + w*64;
            GLD_LDS16(Bt + ((size_t)st*8192 + (size_t)q*8), Bs + qbase*8);
        }
        __syncthreads();

        #pragma unroll
        for (int ks = 0; ks < 2; ks++) {
            short8 a0 = *(const short8*)(&As[((ks*8 + w*2 + 0)*64 + lane)*8]);
            short8 a1 = *(const short8*)(&As[((ks*8 + w*2 + 1)*64 + lane)*8]);
            #pragma unroll
            for (int f = 0; f < 8; f++) {
                short8 bv = *(const short8*)(&Bs[((ks*8 + f)*64 + lane)*8]);
                acc0[f] = __builtin_amdgcn_mfma_f32_16x16x32_bf16(a0, bv, acc0[f], 0, 0, 0);
                acc1[f] = __builtin_amdgcn_mfma_f32_16x16x32_bf16(a1, bv, acc1[f], 0, 0, 0);
            }
        }
        __syncthreads();
    }

    float bv[8], gv[8], bbv[8];
    #pragma unroll
    for (int f = 0; f < 8; f++) {
        bv[f]  = bias[f*16 + l15];
        gv[f]  = lng [f*16 + l15];
        bbv[f] = lnbb[f*16 + l15];
    }
    #pragma unroll
    for (int r2 = 0; r2 < 2; r2++) {
        #pragma unroll
        for (int i = 0; i < 4; i++) {
            int grow = row0 + w*32 + r2*16 + g4*4 + i;
            float vv[8];
            float s = 0.f, sq = 0.f;
            #pragma unroll
            for (int f = 0; f < 8; f++) {
                float av = r2 ? acc1[f][i] : acc0[f][i];
                vv[f] = av + bv[f];
                s  += vv[f];
                sq += vv[f] * vv[f];
            }
            s += __shfl_xor(s, 1);  sq += __shfl_xor(sq, 1);
            s += __shfl_xor(s, 2);  sq += __shfl_xor(sq, 2);
            s += __shfl_xor(s, 4);  sq += __shfl_xor(sq, 4);
            s += __shfl_xor(s, 8);  sq += __shfl_xor(sq, 8);
            float m   = s * (1.f/128.f);
            float var = sq * (1.f/128.f) - m*m;
            float rr  = rsqrtf(var + 1e-5f);
            if (grow < N) {
                #pragma unroll
                for (int f = 0; f < 8; f++) {
                    float y = (vv[f] - m) * rr * gv[f] + bbv[f];
                    y = fmaxf(y, 0.f);
                    out[(size_t)grow*DIM + f*16 + l15] = f2b(y);
                }
            }
        }
    }
}

// ---------------------------------------------------------------------------
// Head: out[N][16] = xp(bf16)[N][128] @ Wh[128][16] + bh.  16 rows/block.
__global__ __launch_bounds__(256) void head_kernel(
    const ushort* __restrict__ xp, const float* __restrict__ Wh,
    const float* __restrict__ bh, float* __restrict__ out)
{
    __shared__ float Xs[16*128];
    __shared__ float Ws[128*16];
    int t = threadIdx.x;
    int row0 = blockIdx.x * 16;
    for (int i = t; i < 2048; i += 256) Ws[i] = Wh[i];
    {
        int r = t >> 4, k8 = (t & 15) * 8;
        int gr = row0 + r;
        if (gr < NPAPER) {
            uint4 v = *(const uint4*)(xp + (size_t)gr*DIM + k8);
            const ushort* pv = (const ushort*)&v;
            #pragma unroll
            for (int i = 0; i < 8; i++) Xs[r*128 + k8 + i] = b2f(pv[i]);
        } else {
            #pragma unroll
            for (int i = 0; i < 8; i++) Xs[r*128 + k8 + i] = 0.f;
        }
    }
    __syncthreads();
    int r = t >> 4, c = t & 15;
    float acc = bh[c];
    #pragma unroll 16
    for (int k = 0; k < 128; k++) acc += Xs[r*128 + k] * Ws[k*16 + c];
    int gr = row0 + r;
    if (gr < NPAPER) out[(size_t)gr*NCLS + c] = acc;
}

// ---------------------------------------------------------------------------
extern "C" void kernel_launch(void* const* d_in, const int* in_sizes, int n_in,
                              void* d_out, int out_size, void* d_ws, size_t ws_size,
                              hipStream_t stream)
{
    const float* x_paper  = (const float*)d_in[0];
    const float* x_author = (const float*)d_in[1];
    const int*   ei_cites = (const int*)d_in[2];
    const int*   ei_writes= (const int*)d_in[3];
    const int*   ei_rev   = (const int*)d_in[4];
    const float* Wl       = (const float*)d_in[5];
    const float* Wr       = (const float*)d_in[6];
    const float* bl       = (const float*)d_in[7];
    const float* linp     = (const float*)d_in[8];
    const float* lina     = (const float*)d_in[9];
    const float* ln_s     = (const float*)d_in[10];
    const float* ln_b     = (const float*)d_in[11];
    const float* Wh       = (const float*)d_in[12];
    const float* bh       = (const float*)d_in[13];
    float* out = (float*)d_out;

    float* ws = (float*)d_ws;
    size_t off = 0;
    float* Bp     = ws + off; off += 2*384*128;
    float* Ba     = ws + off; off += 2*256*128;
    float* biasp  = ws + off; off += 2*128;
    float* biasa  = ws + off; off += 2*128;
    float* biasp2 = ws + off; off += 2*128;
    float* biasa2 = ws + off; off += 2*128;

    ushort* uws = (ushort*)(ws + off);
    size_t uoff = 0;
    ushort* xpb0 = uws + uoff; uoff += (size_t)NPAPER * DIM;
    ushort* xab0 = uws + uoff; uoff += (size_t)NAUTH  * DIM;
    ushort* xpb1 = uws + uoff; uoff += (size_t)NPAPER * DIM;
    ushort* xab1 = uws + uoff; uoff += (size_t)NAUTH  * DIM;
    ushort* aggC = uws + uoff; uoff += (size_t)NPAPER * DIM;
    ushort* aggW = uws + uoff; uoff += (size_t)NPAPER * DIM;
    ushort* aggR = uws + uoff; uoff += (size_t)NAUTH  * DIM;
    ushort* Btp  = uws + uoff; uoff += 2*49152;
    ushort* Bta  = uws + uoff; uoff += 2*32768;
    if (uoff & 3) uoff += 4 - (uoff & 3);   // 8B-align what follows

    uint2* stage = (uint2*)(uws + uoff);    // 3E uint2 = 12 MB
    int* iws = (int*)(stage + 3*NEDGE);
    size_t ioff = 0;
    int* rowAll      = iws + ioff; ioff += NTOT + 1;
    int* colAll      = iws + ioff; ioff += 3*NEDGE;
    int* bucketCount = iws + ioff; ioff += 256;
    int* emitCursor  = iws + ioff; ioff += 256;   // contiguous with bucketCount

    const int TOBF = (NPAPER + NAUTH) * DIM / 4 / 256;   // 18750

    // L0: bucket_count ∥ prep_weights ∥ to_bf16   (zero bucketCount+emitCursor)
    hipMemsetAsync(bucketCount, 0, 512*4, stream);
    misc0<<<NBLK_A + PREPB + TOBF, 256, 0, stream>>>(
        ei_cites, ei_writes, ei_rev, bucketCount,
        Wl, Wr, bl, Bp, Ba, biasp, biasa,
        x_paper, x_author, xpb0, xab0);
    // L1: fold_bias ∥ build_bt ∥ bucket_emit (scan inlined per block)
    misc1<<<2 + BTB + NBLK_A, 256, 0, stream>>>(
        biasp, biasa, linp, lina, biasp2, biasa2,
        Bp, Ba, Btp, Bta,
        ei_cites, ei_writes, ei_rev,
        bucketCount, emitCursor, stage);
    // L2: CSR finalize (scan inlined)
    csr_fillB<<<NB, 256, 0, stream>>>(stage, bucketCount, rowAll, colAll);

    // ---- layer 0 ----
    gather_seg<<<(NTOT + 3)/4, 256, 0, stream>>>(
        0, NTOT, xpb0, xab0, rowAll, colAll, aggC, aggW, aggR);
    gemm_ln2<<<PBLK + ABLK, 256, 0, stream>>>(
        aggC, aggW, aggR, xpb0, xab0,
        Btp, Bta, biasp2, biasa2, ln_s, ln_b,
        xpb1, xab1, PBLK);

    // ---- layer 1 (author path dead: only C+W gathers, paper GEMM) ----
    gather_seg<<<(2*NPAPER + 3)/4, 256, 0, stream>>>(
        0, 2*NPAPER, xpb1, xab1, rowAll, colAll, aggC, aggW, aggR);
    gemm_ln2<<<PBLK, 256, 0, stream>>>(
        aggC, aggW, aggR, xpb1, xab1,
        Btp + 49152, Bta + 32768, biasp2 + 128, biasa2 + 128,
        ln_s + 256, ln_b + 256,
        xpb0, xab0, PBLK);

    // head on layer-1 paper output
    head_kernel<<<(NPAPER + 15)/16, 256, 0, stream>>>(xpb0, Wh, bh, out);
}

// Round 13
// 303.648 us; speedup vs baseline: 1.2041x; 1.2041x over previous
//
#include <hip/hip_runtime.h>
#include <math.h>

#define NPAPER 100000
#define NAUTH  50000
#define DIM    128
#define NEDGE  500000
#define NCLS   16
#define NTOT   (2*NPAPER + NAUTH)   // concatenated CSR node space (C | W | R)
#define NB     245                  // buckets of 1024 nodes over NTOT
#define CHUNK_A 11776               // edges per bucketize block
#define NBLK_A  128                 // ceil(3*NEDGE / CHUNK_A)
#define PBLK   ((NPAPER + 127) / 128)   // 782
#define ABLK   ((NAUTH  + 127) / 128)   // 391

typedef unsigned int   uint;
typedef unsigned short ushort;
typedef unsigned char  uchar;
using short8 = __attribute__((ext_vector_type(8))) short;
using f32x4  = __attribute__((ext_vector_type(4))) float;

__device__ __forceinline__ float b2f(uint u) {
    return __uint_as_float(u << 16);
}
__device__ __forceinline__ ushort f2b(float f) {   // round-to-nearest-even
    uint x = __float_as_uint(f);
    return (ushort)((x + 0x7fffu + ((x >> 16) & 1u)) >> 16);
}

// global_load_lds: linear LDS dest (wave base + lane*16), per-lane global src.
#define GLD_LDS16(srcp, ldsp) \
    __builtin_amdgcn_global_load_lds( \
        (const __attribute__((address_space(1))) void*)(srcp), \
        (__attribute__((address_space(3))) void*)(ldsp), 16, 0, 0)

// ---------------------------------------------------------------------------
// prep bodies (block-indexed device functions, merged into lean misc kernels)
// ---------------------------------------------------------------------------
__device__ __forceinline__ void prep_weights_body(int b, int tid,
    const float* __restrict__ Wl, const float* __restrict__ Wr,
    const float* __restrict__ bl,
    float* __restrict__ Bp, float* __restrict__ Ba,
    float* __restrict__ biasp, float* __restrict__ biasa)
{
    int t = b * 256 + tid;
    if (t < 2*384*128) {
        int l = t / (384*128); int rem = t - l*(384*128);
        int k = rem >> 7, j = rem & 127;
        float v;
        if (k < 128)      v = Wl[((l*3+0)*128 + j)*128 + k];
        else if (k < 256) v = Wl[((l*3+1)*128 + j)*128 + (k-128)];
        else              v = Wr[((l*3+0)*128 + j)*128 + (k-256)]
                            + Wr[((l*3+1)*128 + j)*128 + (k-256)];
        Bp[t] = v;
        return;
    }
    t -= 2*384*128;
    if (t < 2*256*128) {
        int l = t / (256*128); int rem = t - l*(256*128);
        int k = rem >> 7, j = rem & 127;
        Ba[t] = (k < 128) ? Wl[((l*3+2)*128 + j)*128 + k]
                          : Wr[((l*3+2)*128 + j)*128 + (k-128)];
        return;
    }
    t -= 2*256*128;
    if (t < 256) { int l=t>>7, j=t&127; biasp[t] = bl[(l*3+0)*128+j] + bl[(l*3+1)*128+j]; return; }
    t -= 256;
    if (t < 256) { int l=t>>7, j=t&127; biasa[t] = bl[(l*3+2)*128+j]; return; }
}

// residual fold + bf16 + PACK into MFMA-fragment order.
__device__ __forceinline__ size_t pack_off(int j, int k) {
    int kstep = k >> 6, ks = (k >> 5) & 1, g4 = (k >> 3) & 3, jj = k & 7;
    int f = j >> 4, l15 = j & 15;
    return (size_t)kstep*8192 + (size_t)(ks*512 + f*64 + g4*16 + l15)*8 + jj;
}

__device__ __forceinline__ void build_bt_body(int b, int tid,
    const float* __restrict__ Bp, const float* __restrict__ Ba,
    const float* __restrict__ linp, const float* __restrict__ lina,
    ushort* __restrict__ Btp, ushort* __restrict__ Bta)
{
    int t = b * 256 + tid;
    if (t < 2*128*384) {
        int l = t / (128*384); int rem = t - l*(128*384);
        int j = rem / 384, k = rem - j*384;
        const float* brow = Bp + (size_t)l*384*128 + (size_t)k*128;
        float v = brow[j];
        if (l == 0) {
            const float* lrow = linp + (size_t)j*128;
            float s = 0.f;
            #pragma unroll 8
            for (int m = 0; m < 128; m++) s += brow[m] * lrow[m];
            v += s;
        }
        Btp[(size_t)l*49152 + pack_off(j, k)] = f2b(v);
        return;
    }
    t -= 2*128*384;
    if (t < 2*128*256) {
        int l = t / (128*256); int rem = t - l*(128*256);
        int j = rem / 256, k = rem - j*256;
        const float* brow = Ba + (size_t)l*256*128 + (size_t)k*128;
        float v = brow[j];
        if (l == 0) {
            const float* lrow = lina + (size_t)j*128;
            float s = 0.f;
            #pragma unroll 8
            for (int m = 0; m < 128; m++) s += brow[m] * lrow[m];
            v += s;
        }
        Bta[(size_t)l*32768 + pack_off(j, k)] = f2b(v);
    }
}

__device__ __forceinline__ void fold_bias_body(int b, int tid,
    const float* __restrict__ biasp, const float* __restrict__ biasa,
    const float* __restrict__ linp, const float* __restrict__ lina,
    float* __restrict__ biasp2, float* __restrict__ biasa2)
{
    int t = b * 256 + tid;   // 512 total
    int isa = t >> 8; int r = t & 255;
    int l = r >> 7, j = r & 127;
    const float* bsrc = isa ? biasa : biasp;
    const float* lin  = isa ? lina  : linp;
    float v = bsrc[r];
    if (l == 0) {
        float s = 0.f;
        for (int k = 0; k < 128; k++) s += bsrc[k] * lin[j*128 + k];
        v += s;
    }
    (isa ? biasa2 : biasp2)[r] = v;
}

__device__ __forceinline__ void to_bf16_body(int b, int tid,
    const float* __restrict__ xp, const float* __restrict__ xa,
    ushort* __restrict__ yp, ushort* __restrict__ ya)
{
    int i = b * 256 + tid;
    const int n4p = NPAPER * DIM / 4;
    const float* x; ushort* y;
    if (i < n4p) { x = xp; y = yp; }
    else { x = xa; y = ya; i -= n4p; }
    float4 v = ((const float4*)x)[i];
    uint2 o;
    o.x = (uint)f2b(v.x) | ((uint)f2b(v.y) << 16);
    o.y = (uint)f2b(v.z) | ((uint)f2b(v.w) << 16);
    ((uint2*)y)[i] = o;
}

// ---------------------------------------------------------------------------
__device__ __forceinline__ int edge_g(const int* __restrict__ eiC,
                                      const int* __restrict__ eiW,
                                      const int* __restrict__ eiR, int i)
{
    int tpe = (i >= 2*NEDGE) ? 2 : ((i >= NEDGE) ? 1 : 0);
    int e = i - tpe*NEDGE;
    const int* ei = (tpe == 0) ? eiC : ((tpe == 1) ? eiW : eiR);
    int base = (tpe == 0) ? 0 : ((tpe == 1) ? NPAPER : 2*NPAPER);
    return base + ei[NEDGE + e];
}

// misc0: [bucket_count (128) | prep_weights (642) | to_bf16 (18750)]
#define PREPB 642
__global__ __launch_bounds__(256) void misc0(
    const int* __restrict__ eiC, const int* __restrict__ eiW,
    const int* __restrict__ eiR, int* __restrict__ bucketCount,
    const float* __restrict__ Wl, const float* __restrict__ Wr,
    const float* __restrict__ bl,
    float* __restrict__ Bp, float* __restrict__ Ba,
    float* __restrict__ biasp, float* __restrict__ biasa,
    const float* __restrict__ xpf, const float* __restrict__ xaf,
    ushort* __restrict__ xpb, ushort* __restrict__ xab)
{
    __shared__ int h[256];
    int b = blockIdx.x, t = threadIdx.x;
    if (b < NBLK_A) {
        h[t] = 0;
        __syncthreads();
        int start = b * CHUNK_A;
        int n = 3*NEDGE - start; if (n > CHUNK_A) n = CHUNK_A;
        for (int i = t; i < n; i += 256)
            atomicAdd(&h[edge_g(eiC, eiW, eiR, start + i) >> 10], 1);
        __syncthreads();
        if (h[t]) atomicAdd(&bucketCount[t], h[t]);
        return;
    }
    b -= NBLK_A;
    if (b < PREPB) {
        prep_weights_body(b, t, Wl, Wr, bl, Bp, Ba, biasp, biasa);
        return;
    }
    b -= PREPB;
    to_bf16_body(b, t, xpf, xaf, xpb, xab);
}

// misc1: [fold_bias (2) | build_bt (640) | bucket_emit (128)]
// Emit blocks compute the 245-bin exclusive scan redundantly from bucketCount
// (tiny) and reserve per-bucket ranges via zero-initialized emitCursor.
#define BTB 640
__global__ __launch_bounds__(256) void misc1(
    const float* __restrict__ biasp, const float* __restrict__ biasa,
    const float* __restrict__ linp, const float* __restrict__ lina,
    float* __restrict__ biasp2, float* __restrict__ biasa2,
    const float* __restrict__ Bp, const float* __restrict__ Ba,
    ushort* __restrict__ Btp, ushort* __restrict__ Bta,
    const int* __restrict__ eiC, const int* __restrict__ eiW,
    const int* __restrict__ eiR,
    const int* __restrict__ bucketCount, int* __restrict__ emitCursor,
    uint2* __restrict__ stage)
{
    int blk = blockIdx.x, t = threadIdx.x;
    if (blk < 2) {
        fold_bias_body(blk, t, biasp, biasa, linp, lina, biasp2, biasa2);
        return;
    }
    blk -= 2;
    if (blk < BTB) {
        build_bt_body(blk, t, Bp, Ba, linp, lina, Btp, Bta);
        return;
    }
    int b = blk - BTB;

    __shared__ uchar  bId [CHUNK_A];
    __shared__ ushort rnk [CHUNK_A];
    __shared__ ushort perm[CHUNK_A];
    __shared__ uchar  posB[CHUNK_A];
    __shared__ int lcnt[256];
    __shared__ int lpre[256];
    __shared__ int bbase[256];
    __shared__ int bbs[256];

    // redundant exclusive scan of bucketCount -> bucket bases
    {
        int v = (t < NB) ? bucketCount[t] : 0;
        bbs[t] = v;
        __syncthreads();
        for (int o = 1; o < 256; o <<= 1) {
            int x = (t >= o) ? bbs[t - o] : 0;
            __syncthreads();
            bbs[t] += x;
            __syncthreads();
        }
        int inc = bbs[t];
        __syncthreads();
        bbs[t] = inc - ((t < NB) ? bucketCount[t] : 0);   // exclusive
        __syncthreads();
    }

    int start = b * CHUNK_A;
    int n = 3*NEDGE - start; if (n > CHUNK_A) n = CHUNK_A;
    lcnt[t] = 0;
    __syncthreads();
    for (int i = t; i < n; i += 256) {
        int bb = edge_g(eiC, eiW, eiR, start + i) >> 10;
        bId[i] = (uchar)bb;
        rnk[i] = (ushort)atomicAdd(&lcnt[bb], 1);
    }
    __syncthreads();
    lpre[t] = lcnt[t];
    __syncthreads();
    for (int o = 1; o < 256; o <<= 1) {
        int x = (t >= o) ? lpre[t - o] : 0;
        __syncthreads();
        lpre[t] += x;
        __syncthreads();
    }
    if (lcnt[t] > 0) bbase[t] = bbs[t] + atomicAdd(&emitCursor[t], lcnt[t]);
    __syncthreads();
    for (int i = t; i < n; i += 256) {
        int bb = bId[i];
        int p = (lpre[bb] - lcnt[bb]) + rnk[i];
        perm[p] = (ushort)i;
        posB[p] = (uchar)bb;
    }
    __syncthreads();
    for (int p = t; p < n; p += 256) {
        int bb = posB[p];
        int i = start + perm[p];
        int tpe = (i >= 2*NEDGE) ? 2 : ((i >= NEDGE) ? 1 : 0);
        int e = i - tpe*NEDGE;
        const int* ei = (tpe == 0) ? eiC : ((tpe == 1) ? eiW : eiR);
        int base = (tpe == 0) ? 0 : ((tpe == 1) ? NPAPER : 2*NPAPER);
        uint2 o2;
        o2.x = (uint)(base + ei[NEDGE + e]);
        o2.y = (uint)ei[e];
        stage[bbase[bb] + (p - (lpre[bb] - lcnt[bb]))] = o2;
    }
}

// Per-bucket CSR finalize; bucket bases scanned inline from bucketCount.
__global__ __launch_bounds__(256) void csr_fillB(
    const uint2* __restrict__ stage, const int* __restrict__ bucketCount,
    int* __restrict__ rowAll, int* __restrict__ colAll)
{
    __shared__ int cnt[1024];
    __shared__ int part[256];
    __shared__ int bbs[256];
    int b = blockIdx.x;
    int t = threadIdx.x;

    // inline exclusive scan of bucketCount
    {
        int v = (t < NB) ? bucketCount[t] : 0;
        bbs[t] = v;
        __syncthreads();
        for (int o = 1; o < 256; o <<= 1) {
            int x = (t >= o) ? bbs[t - o] : 0;
            __syncthreads();
            bbs[t] += x;
            __syncthreads();
        }
        int inc = bbs[t];
        __syncthreads();
        bbs[t] = inc - ((t < NB) ? bucketCount[t] : 0);
        __syncthreads();
    }
    int g0 = b << 10;
    int nn = NTOT - g0; if (nn > 1024) nn = 1024;
    int s = bbs[b];
    int e = s + bucketCount[b];

    #pragma unroll
    for (int i = t; i < 1024; i += 256) cnt[i] = 0;
    __syncthreads();
    for (int i = s + t; i < e; i += 256) atomicAdd(&cnt[(int)stage[i].x - g0], 1);
    __syncthreads();
    int loc[4]; int ss = 0;
    #pragma unroll
    for (int j = 0; j < 4; j++) { loc[j] = cnt[t*4 + j]; ss += loc[j]; }
    part[t] = ss;
    __syncthreads();
    for (int o = 1; o < 256; o <<= 1) {
        int x = (t >= o) ? part[t - o] : 0;
        __syncthreads();
        part[t] += x;
        __syncthreads();
    }
    int run = (t > 0) ? part[t-1] : 0;
    #pragma unroll
    for (int j = 0; j < 4; j++) { int c = loc[j]; cnt[t*4 + j] = run; run += c; }
    __syncthreads();
    for (int i = t; i < nn; i += 256) rowAll[g0 + i] = s + cnt[i];
    if (b == NB-1 && t == 0) rowAll[NTOT] = 3*NEDGE;
    __syncthreads();
    for (int i = s + t; i < e; i += 256) {
        uint2 ed = stage[i];
        int slot = atomicAdd(&cnt[(int)ed.x - g0], 1);
        colAll[s + slot] = (int)ed.y;
    }
}

// ---------------------------------------------------------------------------
// Gather-mean (round-10 shape): 16 lanes/node, uint4 (16B) row chunks,
// 4-deep load pipeline, dual accumulators -> 16 outstanding row-loads/wave.
__device__ __forceinline__ void acc8(float* a, uint4 v) {
    a[0] += b2f(v.x & 0xffffu); a[1] += b2f(v.x >> 16);
    a[2] += b2f(v.y & 0xffffu); a[3] += b2f(v.y >> 16);
    a[4] += b2f(v.z & 0xffffu); a[5] += b2f(v.z >> 16);
    a[6] += b2f(v.w & 0xffffu); a[7] += b2f(v.w >> 16);
}

__global__ __launch_bounds__(256) void gather_seg(
    int g0, int g1,
    const ushort* __restrict__ xp, const ushort* __restrict__ xa,
    const int* __restrict__ rowAll, const int* __restrict__ colAll,
    ushort* __restrict__ aggC, ushort* __restrict__ aggW,
    ushort* __restrict__ aggR)
{
    int idx = blockIdx.x * 256 + threadIdx.x;
    int g = g0 + (idx >> 4);
    int lane = idx & 15;
    if (g >= g1) return;
    const ushort* xs; ushort* out; int node;
    if (g < NPAPER)        { node = g;            xs = xp; out = aggC; }
    else if (g < 2*NPAPER) { node = g - NPAPER;   xs = xa; out = aggW; }
    else                   { node = g - 2*NPAPER; xs = xp; out = aggR; }

    int s = rowAll[g], e = rowAll[g + 1];
    float a[8] = {0,0,0,0,0,0,0,0};
    float b[8] = {0,0,0,0,0,0,0,0};
    int j = s;
    #pragma unroll 1
    for (; j + 4 <= e; j += 4) {
        int s0 = colAll[j], s1 = colAll[j+1], s2 = colAll[j+2], s3 = colAll[j+3];
        uint4 v0 = *(const uint4*)(xs + (size_t)s0 * DIM + lane * 8);
        uint4 v1 = *(const uint4*)(xs + (size_t)s1 * DIM + lane * 8);
        uint4 v2 = *(const uint4*)(xs + (size_t)s2 * DIM + lane * 8);
        uint4 v3 = *(const uint4*)(xs + (size_t)s3 * DIM + lane * 8);
        acc8(a, v0);
        acc8(b, v1);
        acc8(a, v2);
        acc8(b, v3);
    }
    #pragma unroll 1
    for (; j < e; j++) {
        uint4 v0 = *(const uint4*)(xs + (size_t)colAll[j] * DIM + lane * 8);
        acc8(a, v0);
    }
    float inv = (e > s) ? 1.f / (float)(e - s) : 0.f;
    #pragma unroll
    for (int i = 0; i < 8; i++) a[i] = (a[i] + b[i]) * inv;
    uint4 o;
    o.x = (uint)f2b(a[0]) | ((uint)f2b(a[1]) << 16);
    o.y = (uint)f2b(a[2]) | ((uint)f2b(a[3]) << 16);
    o.z = (uint)f2b(a[4]) | ((uint)f2b(a[5]) << 16);
    o.w = (uint)f2b(a[6]) | ((uint)f2b(a[7]) << 16);
    *(uint4*)(out + (size_t)node * DIM + lane * 8) = o;
}

// ---------------------------------------------------------------------------
// Merged MFMA GEMM + bias + LayerNorm + ReLU.  Blocks [0,pblk): paper rows
// (K=384, segs aggC|aggW|self-p); blocks [pblk,..): author rows (K=256,
// segs aggR|self-a).  256 thr / 4 waves / 128 rows / full N=128 / K-step 64.
__global__ __launch_bounds__(256) void gemm_ln2(
    const ushort* __restrict__ aggC, const ushort* __restrict__ aggW,
    const ushort* __restrict__ aggR,
    const ushort* __restrict__ xp, const ushort* __restrict__ xa,
    const ushort* __restrict__ Btp, const ushort* __restrict__ Bta,
    const float* __restrict__ biasp, const float* __restrict__ biasa,
    const float* __restrict__ lns, const float* __restrict__ lnb,
    ushort* __restrict__ outp, ushort* __restrict__ outa, int pblk)
{
    __shared__ ushort As[8192];   // 16 KB, one K-step
    __shared__ ushort Bs[8192];   // 16 KB

    bool isp = (int)blockIdx.x < pblk;
    int  bid = isp ? blockIdx.x : (blockIdx.x - pblk);
    int  N   = isp ? NPAPER : NAUTH;
    int  K   = isp ? 384 : 256;
    const ushort* A0 = isp ? aggC : aggR;
    const ushort* A1 = isp ? aggW : xa;
    const ushort* A2 = isp ? xp   : xa;
    const ushort* Bt = isp ? Btp  : Bta;
    const float* bias = isp ? biasp : biasa;
    const float* lng  = lns + (isp ? 0 : 128);
    const float* lnbb = lnb + (isp ? 0 : 128);
    ushort* out = isp ? outp : outa;

    int t    = threadIdx.x;
    int w    = t >> 6;
    int lane = t & 63;
    int row0 = bid * 128;
    int l15  = lane & 15;
    int g4   = lane >> 4;

    f32x4 acc0[8], acc1[8];
    #pragma unroll
    for (int f = 0; f < 8; f++) {
        acc0[f] = (f32x4){0.f, 0.f, 0.f, 0.f};
        acc1[f] = (f32x4){0.f, 0.f, 0.f, 0.f};
    }

    int nstep = K >> 6;
    for (int st = 0; st < nstep; st++) {
        int kk  = st << 6;
        int seg = kk >> 7, kl = kk & 127;
        const ushort* Ap = (seg == 0) ? A0 : ((seg == 1) ? A1 : A2);

        #pragma unroll
        for (int p = 0; p < 4; p++) {
            int q  = p*256 + t;
            int ks = q >> 9, rb = (q >> 6) & 7, l = q & 63;
            int row = row0 + rb*16 + (l & 15);
            row = (row < N) ? row : (N - 1);
            int k = kl + ks*32 + (l >> 4)*8;
            int qbase = p*256 + w*64;
            GLD_LDS16(Ap + (size_t)row*DIM + k, As + qbase*8);
        }
        #pragma unroll
        for (int p = 0; p < 4; p++) {
            int q = p*256 + t;
            int qbase = p*256 + w*64;
            GLD_LDS16(Bt + ((size_t)st*8192 + (size_t)q*8), Bs + qbase*8);
        }
        __syncthreads();

        #pragma unroll
        for (int ks = 0; ks < 2; ks++) {
            short8 a0 = *(const short8*)(&As[((ks*8 + w*2 + 0)*64 + lane)*8]);
            short8 a1 = *(const short8*)(&As[((ks*8 + w*2 + 1)*64 + lane)*8]);
            #pragma unroll
            for (int f = 0; f < 8; f++) {
                short8 bv = *(const short8*)(&Bs[((ks*8 + f)*64 + lane)*8]);
                acc0[f] = __builtin_amdgcn_mfma_f32_16x16x32_bf16(a0, bv, acc0[f], 0, 0, 0);
                acc1[f] = __builtin_amdgcn_mfma_f32_16x16x32_bf16(a1, bv, acc1[f], 0, 0, 0);
            }
        }
        __syncthreads();
    }

    float bv[8], gv[8], bbv[8];
    #pragma unroll
    for (int f = 0; f < 8; f++) {
        bv[f]  = bias[f*16 + l15];
        gv[f]  = lng [f*16 + l15];
        bbv[f] = lnbb[f*16 + l15];
    }
    #pragma unroll
    for (int r2 = 0; r2 < 2; r2++) {
        #pragma unroll
        for (int i = 0; i < 4; i++) {
            int grow = row0 + w*32 + r2*16 + g4*4 + i;
            float vv[8];
            float s = 0.f, sq = 0.f;
            #pragma unroll
            for (int f = 0; f < 8; f++) {
                float av = r2 ? acc1[f][i] : acc0[f][i];
                vv[f] = av + bv[f];
                s  += vv[f];
                sq += vv[f] * vv[f];
            }
            s += __shfl_xor(s, 1);  sq += __shfl_xor(sq, 1);
            s += __shfl_xor(s, 2);  sq += __shfl_xor(sq, 2);
            s += __shfl_xor(s, 4);  sq += __shfl_xor(sq, 4);
            s += __shfl_xor(s, 8);  sq += __shfl_xor(sq, 8);
            float m   = s * (1.f/128.f);
            float var = sq * (1.f/128.f) - m*m;
            float rr  = rsqrtf(var + 1e-5f);
            if (grow < N) {
                #pragma unroll
                for (int f = 0; f < 8; f++) {
                    float y = (vv[f] - m) * rr * gv[f] + bbv[f];
                    y = fmaxf(y, 0.f);
                    out[(size_t)grow*DIM + f*16 + l15] = f2b(y);
                }
            }
        }
    }
}

// ---------------------------------------------------------------------------
// Head: out[N][16] = xp(bf16)[N][128] @ Wh[128][16] + bh.  16 rows/block.
__global__ __launch_bounds__(256) void head_kernel(
    const ushort* __restrict__ xp, const float* __restrict__ Wh,
    const float* __restrict__ bh, float* __restrict__ out)
{
    __shared__ float Xs[16*128];
    __shared__ float Ws[128*16];
    int t = threadIdx.x;
    int row0 = blockIdx.x * 16;
    for (int i = t; i < 2048; i += 256) Ws[i] = Wh[i];
    {
        int r = t >> 4, k8 = (t & 15) * 8;
        int gr = row0 + r;
        if (gr < NPAPER) {
            uint4 v = *(const uint4*)(xp + (size_t)gr*DIM + k8);
            const ushort* pv = (const ushort*)&v;
            #pragma unroll
            for (int i = 0; i < 8; i++) Xs[r*128 + k8 + i] = b2f(pv[i]);
        } else {
            #pragma unroll
            for (int i = 0; i < 8; i++) Xs[r*128 + k8 + i] = 0.f;
        }
    }
    __syncthreads();
    int r = t >> 4, c = t & 15;
    float acc = bh[c];
    #pragma unroll 16
    for (int k = 0; k < 128; k++) acc += Xs[r*128 + k] * Ws[k*16 + c];
    int gr = row0 + r;
    if (gr < NPAPER) out[(size_t)gr*NCLS + c] = acc;
}

// ---------------------------------------------------------------------------
extern "C" void kernel_launch(void* const* d_in, const int* in_sizes, int n_in,
                              void* d_out, int out_size, void* d_ws, size_t ws_size,
                              hipStream_t stream)
{
    const float* x_paper  = (const float*)d_in[0];
    const float* x_author = (const float*)d_in[1];
    const int*   ei_cites = (const int*)d_in[2];
    const int*   ei_writes= (const int*)d_in[3];
    const int*   ei_rev   = (const int*)d_in[4];
    const float* Wl       = (const float*)d_in[5];
    const float* Wr       = (const float*)d_in[6];
    const float* bl       = (const float*)d_in[7];
    const float* linp     = (const float*)d_in[8];
    const float* lina     = (const float*)d_in[9];
    const float* ln_s     = (const float*)d_in[10];
    const float* ln_b     = (const float*)d_in[11];
    const float* Wh       = (const float*)d_in[12];
    const float* bh       = (const float*)d_in[13];
    float* out = (float*)d_out;

    float* ws = (float*)d_ws;
    size_t off = 0;
    float* Bp     = ws + off; off += 2*384*128;
    float* Ba     = ws + off; off += 2*256*128;
    float* biasp  = ws + off; off += 2*128;
    float* biasa  = ws + off; off += 2*128;
    float* biasp2 = ws + off; off += 2*128;
    float* biasa2 = ws + off; off += 2*128;

    ushort* uws = (ushort*)(ws + off);
    size_t uoff = 0;
    ushort* xpb0 = uws + uoff; uoff += (size_t)NPAPER * DIM;
    ushort* xab0 = uws + uoff; uoff += (size_t)NAUTH  * DIM;
    ushort* xpb1 = uws + uoff; uoff += (size_t)NPAPER * DIM;
    ushort* xab1 = uws + uoff; uoff += (size_t)NAUTH  * DIM;
    ushort* aggC = uws + uoff; uoff += (size_t)NPAPER * DIM;
    ushort* aggW = uws + uoff; uoff += (size_t)NPAPER * DIM;
    ushort* aggR = uws + uoff; uoff += (size_t)NAUTH  * DIM;
    ushort* Btp  = uws + uoff; uoff += 2*49152;
    ushort* Bta  = uws + uoff; uoff += 2*32768;
    if (uoff & 3) uoff += 4 - (uoff & 3);   // 8B-align what follows

    uint2* stage = (uint2*)(uws + uoff);    // 3E uint2 = 12 MB
    int* iws = (int*)(stage + 3*NEDGE);
    size_t ioff = 0;
    int* rowAll      = iws + ioff; ioff += NTOT + 1;
    int* colAll      = iws + ioff; ioff += 3*NEDGE;
    int* bucketCount = iws + ioff; ioff += 256;
    int* emitCursor  = iws + ioff; ioff += 256;   // contiguous with bucketCount

    const int TOBF = (NPAPER + NAUTH) * DIM / 4 / 256;   // 18750

    // L0: bucket_count ∥ prep_weights ∥ to_bf16   (zero bucketCount+emitCursor)
    hipMemsetAsync(bucketCount, 0, 512*4, stream);
    misc0<<<NBLK_A + PREPB + TOBF, 256, 0, stream>>>(
        ei_cites, ei_writes, ei_rev, bucketCount,
        Wl, Wr, bl, Bp, Ba, biasp, biasa,
        x_paper, x_author, xpb0, xab0);
    // L1: fold_bias ∥ build_bt ∥ bucket_emit (scan inlined per block)
    misc1<<<2 + BTB + NBLK_A, 256, 0, stream>>>(
        biasp, biasa, linp, lina, biasp2, biasa2,
        Bp, Ba, Btp, Bta,
        ei_cites, ei_writes, ei_rev,
        bucketCount, emitCursor, stage);
    // L2: CSR finalize (scan inlined)
    csr_fillB<<<NB, 256, 0, stream>>>(stage, bucketCount, rowAll, colAll);

    // ---- layer 0 ----
    gather_seg<<<(size_t)NTOT*16/256, 256, 0, stream>>>(
        0, NTOT, xpb0, xab0, rowAll, colAll, aggC, aggW, aggR);
    gemm_ln2<<<PBLK + ABLK, 256, 0, stream>>>(
        aggC, aggW, aggR, xpb0, xab0,
        Btp, Bta, biasp2, biasa2, ln_s, ln_b,
        xpb1, xab1, PBLK);

    // ---- layer 1 (author path dead: only C+W gathers, paper GEMM) ----
    gather_seg<<<(size_t)2*NPAPER*16/256, 256, 0, stream>>>(
        0, 2*NPAPER, xpb1, xab1, rowAll, colAll, aggC, aggW, aggR);
    gemm_ln2<<<PBLK, 256, 0, stream>>>(
        aggC, aggW, aggR, xpb1, xab1,
        Btp + 49152, Bta + 32768, biasp2 + 128, biasa2 + 128,
        ln_s + 256, ln_b + 256,
        xpb0, xab0, PBLK);

    // head on layer-1 paper output
    head_kernel<<<(NPAPER + 15)/16, 256, 0, stream>>>(xpb0, Wh, bh, out);
}